// Round 2
// baseline (904.901 us; speedup 1.0000x reference)
//
#include <hip/hip_runtime.h>

#define B_ 4
#define N_ 8192
#define C_ 16
#define JT 512
#define LSTR (JT + 8)   // halves; pad 8 -> 1040 B row stride, conflict-free b128

typedef _Float16 f16;
typedef f16   f16x8 __attribute__((ext_vector_type(8)));
typedef float f32x4 __attribute__((ext_vector_type(4)));
typedef float fv4   __attribute__((ext_vector_type(4)));

// ============ proj_t: hT[b][c][n] = f16( bias[c] + sum_k in[b][n][k] * W[c][k] ) ============
__global__ __launch_bounds__(256) void proj_t_kernel(const float* __restrict__ hin,
                                                     const float* __restrict__ W,
                                                     const float* __restrict__ bias,
                                                     f16* __restrict__ hT) {
    __shared__ float Ws[C_ * C_];
    __shared__ float bs[C_];
    int t = threadIdx.x;
    Ws[t] = W[t];              // blockDim == 256 == C_*C_
    if (t < C_) bs[t] = bias[t];
    __syncthreads();
    int nn = blockIdx.x * 256 + t;       // 0 .. B*N-1
    int b = nn >> 13, n = nn & (N_ - 1);
    const fv4* hv = (const fv4*)(hin + (size_t)nn * C_);
    fv4 q0 = hv[0], q1 = hv[1], q2 = hv[2], q3 = hv[3];
    float hr[16] = {q0[0], q0[1], q0[2], q0[3], q1[0], q1[1], q1[2], q1[3],
                    q2[0], q2[1], q2[2], q2[3], q3[0], q3[1], q3[2], q3[3]};
    f16* dst = hT + ((size_t)b * C_) * N_ + n;
#pragma unroll
    for (int c = 0; c < 16; ++c) {
        float s = bs[c];
#pragma unroll
        for (int k = 0; k < 16; ++k) s += hr[k] * Ws[c * 16 + k];
        dst[(size_t)c * N_] = (f16)s;
    }
}

// ============ agg via MFMA: g[b,i,:] = relu( (adj[b,i,:] @ h) / deg[b,i] ) ============
// L1: reads fp32 adj, writes f16 copy + deg. L2/3: reads f16 copy + deg.
// Wave owns 16 rows; block = 4 waves = 64 rows. B staged in LDS transposed [c][k].
template <bool L1>
__global__ __launch_bounds__(256) void agg_mfma_kernel(const float* __restrict__ adjf,
                                                       const f16* __restrict__ adjh,
                                                       f16* __restrict__ adjh_out,
                                                       const f16* __restrict__ hT,
                                                       float* __restrict__ gout,
                                                       float* __restrict__ deg) {
    __shared__ f16 hs[2][C_][LSTR];
    const int b = blockIdx.y;
    const int i0 = blockIdx.x * 64;
    const int t = threadIdx.x;
    const int wave = t >> 6, lane = t & 63;
    const int m = lane & 15, kg = lane >> 4;
    const int rowbase = i0 + wave * 16;
    const int row = rowbase + m;

    const size_t arow = ((size_t)b * N_ + row) * N_;
    const f16* hTb = hT + (size_t)b * C_ * N_;

    f32x4 acc = {0.f, 0.f, 0.f, 0.f};
    float dsum = 0.f;

    const int srow = t >> 4;    // 0..15 staging row (channel)
    const int schunk = t & 15;  // 0..15

    auto stage = [&](int buf, int jt) {
        const f16* src = hTb + (size_t)srow * N_ + jt + schunk * 8;
#pragma unroll
        for (int k = 0; k < 4; ++k) {
            f16x8 v = *(const f16x8*)(src + k * 128);
            *(f16x8*)&hs[buf][srow][schunk * 8 + k * 128] = v;
        }
    };

    stage(0, 0);
    const int nt = N_ / JT;  // 16
    for (int tile = 0; tile < nt; ++tile) {
        __syncthreads();
        if (tile + 1 < nt) stage((tile + 1) & 1, (tile + 1) * JT);
        const int buf = tile & 1;
        const int jt = tile * JT;
#pragma unroll
        for (int ks = 0; ks < JT / 32; ++ks) {
            const int k = jt + ks * 32 + kg * 8;
            f16x8 a;
            if (L1) {
                fv4 f0 = __builtin_nontemporal_load((const fv4*)(adjf + arow + k));
                fv4 f1 = __builtin_nontemporal_load((const fv4*)(adjf + arow + k) + 1);
                a[0] = (f16)f0[0]; a[1] = (f16)f0[1]; a[2] = (f16)f0[2]; a[3] = (f16)f0[3];
                a[4] = (f16)f1[0]; a[5] = (f16)f1[1]; a[6] = (f16)f1[2]; a[7] = (f16)f1[3];
                __builtin_nontemporal_store(a, (f16x8*)(adjh_out + arow + k));
                dsum += ((f0[0] + f0[1]) + (f0[2] + f0[3])) + ((f1[0] + f1[1]) + (f1[2] + f1[3]));
            } else {
                a = __builtin_nontemporal_load((const f16x8*)(adjh + arow + k));
            }
            f16x8 bf = *(const f16x8*)&hs[buf][m][ks * 32 + kg * 8];
            acc = __builtin_amdgcn_mfma_f32_16x16x32_f16(a, bf, acc, 0, 0, 0);
        }
    }

    float dv[4];
    if (L1) {
        dsum += __shfl_xor(dsum, 16, 64);
        dsum += __shfl_xor(dsum, 32, 64);
        // lane m holds deg(rowbase + m)
        if (lane < 16) deg[(size_t)b * N_ + rowbase + lane] = dsum;
#pragma unroll
        for (int r = 0; r < 4; ++r) dv[r] = __shfl(dsum, kg * 4 + r, 64);
    } else {
#pragma unroll
        for (int r = 0; r < 4; ++r) dv[r] = deg[(size_t)b * N_ + rowbase + kg * 4 + r];
    }
#pragma unroll
    for (int r = 0; r < 4; ++r) {
        float v = acc[r] / dv[r];
        v = v > 0.f ? v : 0.f;
        // C/D layout (m89-verified): col = lane&15, row = (lane>>4)*4 + reg
        gout[((size_t)b * N_ + rowbase + kg * 4 + r) * C_ + m] = v;
    }
}

// ============ final: out[b,o] = b_fl[o] + sum_m g[b,m] * W_fl[o,m] ============
__global__ __launch_bounds__(1024) void final_kernel(const float* __restrict__ h,
                                                     const float* __restrict__ Wfl,
                                                     const float* __restrict__ bfl,
                                                     float* __restrict__ out) {
    const int b = blockIdx.x >> 1;
    const int o = blockIdx.x & 1;
    const fv4* hv = (const fv4*)(h + (size_t)b * N_ * C_);
    const fv4* wv = (const fv4*)(Wfl + (size_t)o * N_ * C_);
    float s = 0.f;
    for (int m = threadIdx.x; m < (N_ * C_) / 4; m += 1024) {
        fv4 a = hv[m], w = wv[m];
        s += a[0] * w[0] + a[1] * w[1] + a[2] * w[2] + a[3] * w[3];
    }
    for (int msk = 32; msk >= 1; msk >>= 1) s += __shfl_xor(s, msk, 64);
    __shared__ float wsum[16];
    int wave = threadIdx.x >> 6, lane = threadIdx.x & 63;
    if (lane == 0) wsum[wave] = s;
    __syncthreads();
    if (threadIdx.x == 0) {
        float tot = bfl[o];
#pragma unroll
        for (int w = 0; w < 16; ++w) tot += wsum[w];
        out[b * 2 + o] = tot;
    }
}

// ===================== fallback (round-1 fp32 path, known-passing) =====================
__global__ __launch_bounds__(256) void proj_kernel(const float* __restrict__ hin,
                                                   const float* __restrict__ W,
                                                   const float* __restrict__ bias,
                                                   float* __restrict__ hout,
                                                   int total_nodes) {
    __shared__ float Ws[C_ * C_];
    __shared__ float bs[C_];
    int t = threadIdx.x;
    if (t < C_ * C_) Ws[t] = W[t];
    if (t < C_) bs[t] = bias[t];
    __syncthreads();
    int n = blockIdx.x * 256 + t;
    if (n >= total_nodes) return;
    const fv4* hv = (const fv4*)(hin + (size_t)n * C_);
    fv4 q0 = hv[0], q1 = hv[1], q2 = hv[2], q3 = hv[3];
    float hr[16] = {q0[0], q0[1], q0[2], q0[3], q1[0], q1[1], q1[2], q1[3],
                    q2[0], q2[1], q2[2], q2[3], q3[0], q3[1], q3[2], q3[3]};
    float o[16];
#pragma unroll
    for (int c = 0; c < 16; ++c) {
        float s = bs[c];
#pragma unroll
        for (int k = 0; k < 16; ++k) s += hr[k] * Ws[c * 16 + k];
        o[c] = s;
    }
    fv4* ov = (fv4*)(hout + (size_t)n * C_);
    ov[0] = fv4{o[0], o[1], o[2], o[3]};
    ov[1] = fv4{o[4], o[5], o[6], o[7]};
    ov[2] = fv4{o[8], o[9], o[10], o[11]};
    ov[3] = fv4{o[12], o[13], o[14], o[15]};
}

__global__ __launch_bounds__(256) void agg_kernel_f32(const float* __restrict__ adj,
                                                      const float* __restrict__ hin,
                                                      float* __restrict__ hout) {
    __shared__ fv4 hsf[JT][5];
    const int b = blockIdx.y;
    const int i0 = blockIdx.x * 16;
    const int t = threadIdx.x;
    const int wave = t >> 6;
    const int lane = t & 63;
    const int r0 = i0 + wave * 4;
    const float* adjb = adj + (size_t)b * N_ * N_;
    const float* hb = hin + (size_t)b * N_ * C_;
    const float* ar[4];
#pragma unroll
    for (int r = 0; r < 4; ++r) ar[r] = adjb + (size_t)(r0 + r) * N_;
    float acc[4][16];
#pragma unroll
    for (int r = 0; r < 4; ++r)
#pragma unroll
        for (int c = 0; c < 16; ++c) acc[r][c] = 0.f;
    float rs[4] = {0.f, 0.f, 0.f, 0.f};
    for (int jt = 0; jt < N_; jt += JT) {
        const fv4* src = (const fv4*)(hb + (size_t)jt * C_);
#pragma unroll
        for (int k = 0; k < (JT * C_ / 4) / 256; ++k) {
            int g = t + k * 256;
            hsf[g >> 2][g & 3] = src[g];
        }
        __syncthreads();
#pragma unroll 2
        for (int jj = lane; jj < JT; jj += 64) {
            fv4 q0 = hsf[jj][0], q1 = hsf[jj][1], q2 = hsf[jj][2], q3 = hsf[jj][3];
            float hv[16] = {q0[0], q0[1], q0[2], q0[3], q1[0], q1[1], q1[2], q1[3],
                            q2[0], q2[1], q2[2], q2[3], q3[0], q3[1], q3[2], q3[3]};
#pragma unroll
            for (int r = 0; r < 4; ++r) {
                float av = ar[r][jt + jj];
                rs[r] += av;
#pragma unroll
                for (int c = 0; c < 16; ++c) acc[r][c] += av * hv[c];
            }
        }
        __syncthreads();
    }
#pragma unroll
    for (int r = 0; r < 4; ++r) {
#pragma unroll
        for (int c = 0; c < 16; ++c) {
            float v = acc[r][c];
            for (int mm = 32; mm >= 1; mm >>= 1) v += __shfl_xor(v, mm, 64);
            acc[r][c] = v;
        }
        float d = rs[r];
        for (int mm = 32; mm >= 1; mm >>= 1) d += __shfl_xor(d, mm, 64);
        rs[r] = d;
    }
    if (lane == 0) {
#pragma unroll
        for (int r = 0; r < 4; ++r) {
            float inv = 1.0f / rs[r];
            fv4* dst = (fv4*)(hout + (size_t)b * N_ * C_ + (size_t)(r0 + r) * C_);
#pragma unroll
            for (int q = 0; q < 4; ++q) {
                fv4 ov;
#pragma unroll
                for (int e = 0; e < 4; ++e) {
                    float v = acc[r][q * 4 + e] * inv;
                    ov[e] = v > 0.f ? v : 0.f;
                }
                dst[q] = ov;
            }
        }
    }
}

// ========================================================================================
extern "C" void kernel_launch(void* const* d_in, const int* in_sizes, int n_in,
                              void* d_out, int out_size, void* d_ws, size_t ws_size,
                              hipStream_t stream) {
    const float* x   = (const float*)d_in[0];
    const float* adj = (const float*)d_in[1];
    const float* Wp  = (const float*)d_in[2];
    const float* bp  = (const float*)d_in[3];
    const float* Wfl = (const float*)d_in[4];
    const float* bfl = (const float*)d_in[5];
    float* out = (float*)d_out;

    const size_t adjh_b = (size_t)B_ * N_ * N_ * sizeof(f16);  // 512 MB
    const size_t deg_b  = (size_t)B_ * N_ * sizeof(float);
    const size_t hT_b   = (size_t)B_ * C_ * N_ * sizeof(f16);
    const size_t g_b    = (size_t)B_ * N_ * C_ * sizeof(float);

    if (ws_size >= adjh_b + deg_b + hT_b + g_b) {
        char* p = (char*)d_ws;
        f16* adjh  = (f16*)p;    p += adjh_b;
        float* deg = (float*)p;  p += deg_b;
        f16* hT    = (f16*)p;    p += hT_b;
        float* g   = (float*)p;

        dim3 ag(N_ / 64, B_);
        const int pblocks = B_ * N_ / 256;

        proj_t_kernel<<<pblocks, 256, 0, stream>>>(x, Wp, bp, hT);
        agg_mfma_kernel<true><<<ag, 256, 0, stream>>>(adj, nullptr, adjh, hT, g, deg);
        proj_t_kernel<<<pblocks, 256, 0, stream>>>(g, Wp, bp, hT);
        agg_mfma_kernel<false><<<ag, 256, 0, stream>>>(nullptr, adjh, nullptr, hT, g, deg);
        proj_t_kernel<<<pblocks, 256, 0, stream>>>(g, Wp, bp, hT);
        agg_mfma_kernel<false><<<ag, 256, 0, stream>>>(nullptr, adjh, nullptr, hT, g, deg);
        final_kernel<<<B_ * 2, 1024, 0, stream>>>(g, Wfl, bfl, out);
    } else {
        // fallback: fp32 pipeline (needs only 4 MB)
        float* hA = (float*)d_ws;
        float* hB = hA + (size_t)B_ * N_ * C_;
        const int nodes = B_ * N_;
        dim3 aggGrid(N_ / 16, B_);
        proj_kernel<<<(nodes + 255) / 256, 256, 0, stream>>>(x, Wp, bp, hA, nodes);
        agg_kernel_f32<<<aggGrid, 256, 0, stream>>>(adj, hA, hB);
        proj_kernel<<<(nodes + 255) / 256, 256, 0, stream>>>(hB, Wp, bp, hA, nodes);
        agg_kernel_f32<<<aggGrid, 256, 0, stream>>>(adj, hA, hB);
        proj_kernel<<<(nodes + 255) / 256, 256, 0, stream>>>(hB, Wp, bp, hA, nodes);
        agg_kernel_f32<<<aggGrid, 256, 0, stream>>>(adj, hA, hB);
        final_kernel<<<B_ * 2, 1024, 0, stream>>>(hB, Wfl, bfl, out);
    }
}

// Round 4
// 614.215 us; speedup vs baseline: 1.4733x; 1.4733x over previous
//
#include <hip/hip_runtime.h>

#define B_ 4
#define N_ 8192
#define C_ 16
#define JT 512
#define NT (N_ / JT)     // 16 tiles
#define LSTR (JT + 8)    // 520 halves row stride in LDS

typedef _Float16 f16;
typedef f16   f16x2 __attribute__((ext_vector_type(2)));
typedef f16   f16x8 __attribute__((ext_vector_type(8)));
typedef float fv4   __attribute__((ext_vector_type(4)));

union v8u { f16x8 v8; f16x2 v2[4]; };

// v_dot2_f32_f16: d = a.x*b.x + a.y*b.y + c (f32 accumulate, full-rate VALU)
__device__ __forceinline__ float fdot2(f16x2 a, f16x2 b, float c) {
    float d;
    asm("v_dot2_f32_f16 %0, %1, %2, %3" : "=v"(d) : "v"(a), "v"(b), "v"(c));
    return d;
}

// acc += dot(a.v8, h.v8) with literal-constant pair indices
#define DOT8(accv, au, hu)                         \
    do {                                           \
        accv = fdot2((au).v2[0], (hu).v2[0], accv); \
        accv = fdot2((au).v2[1], (hu).v2[1], accv); \
        accv = fdot2((au).v2[2], (hu).v2[2], accv); \
        accv = fdot2((au).v2[3], (hu).v2[3], accv); \
    } while (0)

// ============ proj_t: hT[b][c][n] = f16( bias[c] + sum_k in[b][n][k] * W[c][k] ) ============
__global__ __launch_bounds__(256) void proj_t_kernel(const float* __restrict__ hin,
                                                     const float* __restrict__ W,
                                                     const float* __restrict__ bias,
                                                     f16* __restrict__ hT) {
    __shared__ float Ws[C_ * C_];
    __shared__ float bs[C_];
    int t = threadIdx.x;
    Ws[t] = W[t];
    if (t < C_) bs[t] = bias[t];
    __syncthreads();
    int nn = blockIdx.x * 256 + t;
    int b = nn >> 13, n = nn & (N_ - 1);
    const fv4* hv = (const fv4*)(hin + (size_t)nn * C_);
    fv4 q0 = hv[0], q1 = hv[1], q2 = hv[2], q3 = hv[3];
    float hr[16] = {q0[0], q0[1], q0[2], q0[3], q1[0], q1[1], q1[2], q1[3],
                    q2[0], q2[1], q2[2], q2[3], q3[0], q3[1], q3[2], q3[3]};
    f16* dst = hT + ((size_t)b * C_) * N_ + n;
#pragma unroll
    for (int c = 0; c < 16; ++c) {
        float s = bs[c];
#pragma unroll
        for (int k = 0; k < 16; ++k) s += hr[k] * Ws[c * 16 + k];
        dst[(size_t)c * N_] = (f16)s;
    }
}

// ============ agg (coalesced, dot2):
// MODE 0: read fp32 adj, write f16 adj + deg, fused proj -> hTout
// MODE 1: read f16 adj + deg,                fused proj -> hTout
// MODE 2: read f16 adj + deg,                write g fp32 (layer-3 output)
template <int MODE>
__global__ __launch_bounds__(256) void agg_kernel(const float* __restrict__ adjf,
                                                  const f16* __restrict__ adjh,
                                                  f16* __restrict__ adjh_out,
                                                  const f16* __restrict__ hTin,
                                                  float* __restrict__ deg,
                                                  const float* __restrict__ Wp,
                                                  const float* __restrict__ bp,
                                                  f16* __restrict__ hTout,
                                                  float* __restrict__ gout) {
    __shared__ f16 hs[2][C_][LSTR];
    __shared__ float Ws[C_ * C_ + C_];
    __shared__ float accL[4][4][C_ + 1];

    const int b = blockIdx.y;
    const int i0 = blockIdx.x * 16;
    const int t = threadIdx.x;
    const int wave = t >> 6, lane = t & 63;
    const int r0 = i0 + wave * 4;

    if (MODE < 2) {
        Ws[t] = Wp[t];
        if (t < C_) Ws[C_ * C_ + t] = bp[t];
    }

    float dv[4];
    if (MODE > 0) {
#pragma unroll
        for (int r = 0; r < 4; ++r) dv[r] = deg[(size_t)b * N_ + r0 + r];
    }

    const f16* hTb = hTin + (size_t)b * C_ * N_;
    const int srow = t >> 4, schunk = t & 15;

    auto stage = [&](int buf, int jt) {
        const f16* src = hTb + (size_t)srow * N_ + jt + schunk * 8;
#pragma unroll
        for (int k = 0; k < 4; ++k) {
            f16x8 v = *(const f16x8*)(src + k * 128);
            *(f16x8*)&hs[buf][srow][schunk * 8 + k * 128] = v;
        }
    };

    size_t arow[4];
#pragma unroll
    for (int r = 0; r < 4; ++r) arow[r] = ((size_t)b * N_ + (r0 + r)) * (size_t)N_;

    float acc[4][C_];
#pragma unroll
    for (int r = 0; r < 4; ++r)
#pragma unroll
        for (int c = 0; c < C_; ++c) acc[r][c] = 0.f;
    float ds4[4] = {0.f, 0.f, 0.f, 0.f};
    const f16x2 ones = {(f16)1.f, (f16)1.f};

    stage(0, 0);
    for (int tile = 0; tile < NT; ++tile) {
        __syncthreads();
        if (tile + 1 < NT) stage((tile + 1) & 1, (tile + 1) * JT);
        const int buf = tile & 1;
        const int jb = tile * JT + lane * 8;

        v8u av[4];
        if (MODE == 0) {
#pragma unroll
            for (int r = 0; r < 4; ++r) {
                fv4 f0 = __builtin_nontemporal_load((const fv4*)(adjf + arow[r] + jb));
                fv4 f1 = __builtin_nontemporal_load((const fv4*)(adjf + arow[r] + jb) + 1);
                f16x8 a;
                a[0] = (f16)f0[0]; a[1] = (f16)f0[1]; a[2] = (f16)f0[2]; a[3] = (f16)f0[3];
                a[4] = (f16)f1[0]; a[5] = (f16)f1[1]; a[6] = (f16)f1[2]; a[7] = (f16)f1[3];
                __builtin_nontemporal_store(a, (f16x8*)(adjh_out + arow[r] + jb));
                av[r].v8 = a;
            }
#pragma unroll
            for (int r = 0; r < 4; ++r) {
                v8u on; on.v2[0] = ones; on.v2[1] = ones; on.v2[2] = ones; on.v2[3] = ones;
                DOT8(ds4[r], av[r], on);
            }
        } else {
#pragma unroll
            for (int r = 0; r < 4; ++r)
                av[r].v8 = __builtin_nontemporal_load((const f16x8*)(adjh + arow[r] + jb));
        }

#pragma unroll
        for (int c = 0; c < C_; ++c) {
            v8u hu;
            hu.v8 = *(const f16x8*)&hs[buf][c][lane * 8];
            DOT8(acc[0][c], av[0], hu);
            DOT8(acc[1][c], av[1], hu);
            DOT8(acc[2][c], av[2], hu);
            DOT8(acc[3][c], av[3], hu);
        }
    }

    // butterfly reduce across 64 lanes (every lane ends with the full sum)
#pragma unroll
    for (int r = 0; r < 4; ++r)
#pragma unroll
        for (int c = 0; c < C_; ++c) {
            float v = acc[r][c];
#pragma unroll
            for (int m = 32; m >= 1; m >>= 1) v += __shfl_xor(v, m, 64);
            acc[r][c] = v;
        }
    if (MODE == 0) {
#pragma unroll
        for (int r = 0; r < 4; ++r) {
            float v = ds4[r];
#pragma unroll
            for (int m = 32; m >= 1; m >>= 1) v += __shfl_xor(v, m, 64);
            dv[r] = v;
        }
        if (lane == 0) {
#pragma unroll
            for (int r = 0; r < 4; ++r) deg[(size_t)b * N_ + r0 + r] = dv[r];
        }
    }

    // LDS bounce so the epilogue can index the c-dimension dynamically (rule #20)
    if (lane == 0) {
#pragma unroll
        for (int r = 0; r < 4; ++r)
#pragma unroll
            for (int c = 0; c < C_; ++c) accL[wave][r][c] = acc[r][c];
    }
    __syncthreads();

    if (lane < C_) {
        const int ec = lane;
        if (MODE < 2) {
#pragma unroll
            for (int r = 0; r < 4; ++r) {
                float p = Ws[C_ * C_ + ec];
#pragma unroll
                for (int c = 0; c < C_; ++c) {
                    float o = accL[wave][r][c] / dv[r];
                    o = o > 0.f ? o : 0.f;
                    p += o * Ws[ec * C_ + c];
                }
                hTout[(size_t)b * C_ * N_ + (size_t)ec * N_ + (r0 + r)] = (f16)p;
            }
        } else {
#pragma unroll
            for (int r = 0; r < 4; ++r) {
                float o = accL[wave][r][ec] / dv[r];
                o = o > 0.f ? o : 0.f;
                gout[((size_t)b * N_ + r0 + r) * C_ + ec] = o;
            }
        }
    }
}

// ============ final: two-stage deterministic reduction ============
__global__ __launch_bounds__(256) void final_partial(const float* __restrict__ g,
                                                     const float* __restrict__ Wfl,
                                                     float* __restrict__ partial) {
    const int bx = blockIdx.x;                 // b*32 + o*16 + chunk
    const int b = bx >> 5, o = (bx >> 4) & 1, chunk = bx & 15;
    const size_t base = (size_t)chunk * 8192;  // elements of m (fv4-aligned)
    const fv4* hv = (const fv4*)(g + (size_t)b * N_ * C_ + base);
    const fv4* wv = (const fv4*)(Wfl + (size_t)o * N_ * C_ + base);
    float s = 0.f;
#pragma unroll
    for (int k = 0; k < 8; ++k) {
        int idx = threadIdx.x + k * 256;       // 2048 fv4 per chunk
        fv4 a = hv[idx], w = wv[idx];
        s += a[0] * w[0] + a[1] * w[1] + a[2] * w[2] + a[3] * w[3];
    }
#pragma unroll
    for (int m = 32; m >= 1; m >>= 1) s += __shfl_xor(s, m, 64);
    __shared__ float wsum[4];
    if ((threadIdx.x & 63) == 0) wsum[threadIdx.x >> 6] = s;
    __syncthreads();
    if (threadIdx.x == 0) partial[bx] = wsum[0] + wsum[1] + wsum[2] + wsum[3];
}

__global__ void final_reduce(const float* __restrict__ partial,
                             const float* __restrict__ bfl,
                             float* __restrict__ out) {
    int i = threadIdx.x;
    if (i < B_ * 2) {
        float s = bfl[i & 1];
        for (int k = 0; k < 16; ++k) s += partial[i * 16 + k];
        out[i] = s;
    }
}

// ===================== fallback (round-1 fp32 path, known-passing) =====================
__global__ __launch_bounds__(256) void proj_kernel(const float* __restrict__ hin,
                                                   const float* __restrict__ W,
                                                   const float* __restrict__ bias,
                                                   float* __restrict__ hout,
                                                   int total_nodes) {
    __shared__ float Ws[C_ * C_];
    __shared__ float bs[C_];
    int t = threadIdx.x;
    if (t < C_ * C_) Ws[t] = W[t];
    if (t < C_) bs[t] = bias[t];
    __syncthreads();
    int n = blockIdx.x * 256 + t;
    if (n >= total_nodes) return;
    const fv4* hv = (const fv4*)(hin + (size_t)n * C_);
    fv4 q0 = hv[0], q1 = hv[1], q2 = hv[2], q3 = hv[3];
    float hr[16] = {q0[0], q0[1], q0[2], q0[3], q1[0], q1[1], q1[2], q1[3],
                    q2[0], q2[1], q2[2], q2[3], q3[0], q3[1], q3[2], q3[3]};
    float o[16];
#pragma unroll
    for (int c = 0; c < 16; ++c) {
        float s = bs[c];
#pragma unroll
        for (int k = 0; k < 16; ++k) s += hr[k] * Ws[c * 16 + k];
        o[c] = s;
    }
    fv4* ov = (fv4*)(hout + (size_t)n * C_);
    ov[0] = fv4{o[0], o[1], o[2], o[3]};
    ov[1] = fv4{o[4], o[5], o[6], o[7]};
    ov[2] = fv4{o[8], o[9], o[10], o[11]};
    ov[3] = fv4{o[12], o[13], o[14], o[15]};
}

__global__ __launch_bounds__(256) void agg_kernel_f32(const float* __restrict__ adj,
                                                      const float* __restrict__ hin,
                                                      float* __restrict__ hout) {
    __shared__ fv4 hsf[JT][5];
    const int b = blockIdx.y;
    const int i0 = blockIdx.x * 16;
    const int t = threadIdx.x;
    const int wave = t >> 6;
    const int lane = t & 63;
    const int r0 = i0 + wave * 4;
    const float* adjb = adj + (size_t)b * N_ * N_;
    const float* hb = hin + (size_t)b * N_ * C_;
    const float* ar[4];
#pragma unroll
    for (int r = 0; r < 4; ++r) ar[r] = adjb + (size_t)(r0 + r) * N_;
    float acc[4][16];
#pragma unroll
    for (int r = 0; r < 4; ++r)
#pragma unroll
        for (int c = 0; c < 16; ++c) acc[r][c] = 0.f;
    float rs[4] = {0.f, 0.f, 0.f, 0.f};
    for (int jt = 0; jt < N_; jt += JT) {
        const fv4* src = (const fv4*)(hb + (size_t)jt * C_);
#pragma unroll
        for (int k = 0; k < (JT * C_ / 4) / 256; ++k) {
            int g = t + k * 256;
            hsf[g >> 2][g & 3] = src[g];
        }
        __syncthreads();
#pragma unroll 2
        for (int jj = lane; jj < JT; jj += 64) {
            fv4 q0 = hsf[jj][0], q1 = hsf[jj][1], q2 = hsf[jj][2], q3 = hsf[jj][3];
            float hv[16] = {q0[0], q0[1], q0[2], q0[3], q1[0], q1[1], q1[2], q1[3],
                            q2[0], q2[1], q2[2], q2[3], q3[0], q3[1], q3[2], q3[3]};
#pragma unroll
            for (int r = 0; r < 4; ++r) {
                float av = ar[r][jt + jj];
                rs[r] += av;
#pragma unroll
                for (int c = 0; c < 16; ++c) acc[r][c] += av * hv[c];
            }
        }
        __syncthreads();
    }
#pragma unroll
    for (int r = 0; r < 4; ++r) {
#pragma unroll
        for (int c = 0; c < 16; ++c) {
            float v = acc[r][c];
            for (int mm = 32; mm >= 1; mm >>= 1) v += __shfl_xor(v, mm, 64);
            acc[r][c] = v;
        }
        float d = rs[r];
        for (int mm = 32; mm >= 1; mm >>= 1) d += __shfl_xor(d, mm, 64);
        rs[r] = d;
    }
    if (lane == 0) {
#pragma unroll
        for (int r = 0; r < 4; ++r) {
            float inv = 1.0f / rs[r];
            fv4* dst = (fv4*)(hout + (size_t)b * N_ * C_ + (size_t)(r0 + r) * C_);
#pragma unroll
            for (int q = 0; q < 4; ++q) {
                fv4 ov;
#pragma unroll
                for (int e = 0; e < 4; ++e) {
                    float v = acc[r][q * 4 + e] * inv;
                    ov[e] = v > 0.f ? v : 0.f;
                }
                dst[q] = ov;
            }
        }
    }
}

// ========================================================================================
extern "C" void kernel_launch(void* const* d_in, const int* in_sizes, int n_in,
                              void* d_out, int out_size, void* d_ws, size_t ws_size,
                              hipStream_t stream) {
    const float* x   = (const float*)d_in[0];
    const float* adj = (const float*)d_in[1];
    const float* Wp  = (const float*)d_in[2];
    const float* bp  = (const float*)d_in[3];
    const float* Wfl = (const float*)d_in[4];
    const float* bfl = (const float*)d_in[5];
    float* out = (float*)d_out;

    const size_t adjh_b = (size_t)B_ * N_ * N_ * sizeof(f16);   // 512 MB
    const size_t deg_b  = (size_t)B_ * N_ * sizeof(float);      // 128 KB
    const size_t hT_b   = (size_t)B_ * C_ * N_ * sizeof(f16);   // 1 MB
    const size_t g_b    = (size_t)B_ * N_ * C_ * sizeof(float); // 2 MB
    const size_t part_b = 128 * sizeof(float);

    if (ws_size >= adjh_b + deg_b + 2 * hT_b + g_b + part_b) {
        char* p = (char*)d_ws;
        f16* adjh      = (f16*)p;   p += adjh_b;
        float* deg     = (float*)p; p += deg_b;
        f16* hTa       = (f16*)p;   p += hT_b;
        f16* hTb       = (f16*)p;   p += hT_b;
        float* g       = (float*)p; p += g_b;
        float* partial = (float*)p;

        dim3 ag(N_ / 16, B_);
        const int pblocks = B_ * N_ / 256;

        proj_t_kernel<<<pblocks, 256, 0, stream>>>(x, Wp, bp, hTa);
        agg_kernel<0><<<ag, 256, 0, stream>>>(adj, nullptr, adjh, hTa, deg, Wp, bp, hTb, nullptr);
        agg_kernel<1><<<ag, 256, 0, stream>>>(nullptr, adjh, nullptr, hTb, deg, Wp, bp, hTa, nullptr);
        agg_kernel<2><<<ag, 256, 0, stream>>>(nullptr, adjh, nullptr, hTa, deg, Wp, bp, nullptr, g);
        final_partial<<<B_ * 32, 256, 0, stream>>>(g, Wfl, partial);
        final_reduce<<<1, 64, 0, stream>>>(partial, bfl, out);
    } else {
        float* hA = (float*)d_ws;
        float* hB = hA + (size_t)B_ * N_ * C_;
        float* partial = hB + (size_t)B_ * N_ * C_;
        const int nodes = B_ * N_;
        dim3 aggGrid(N_ / 16, B_);
        proj_kernel<<<(nodes + 255) / 256, 256, 0, stream>>>(x, Wp, bp, hA, nodes);
        agg_kernel_f32<<<aggGrid, 256, 0, stream>>>(adj, hA, hB);
        proj_kernel<<<(nodes + 255) / 256, 256, 0, stream>>>(hB, Wp, bp, hA, nodes);
        agg_kernel_f32<<<aggGrid, 256, 0, stream>>>(adj, hA, hB);
        proj_kernel<<<(nodes + 255) / 256, 256, 0, stream>>>(hB, Wp, bp, hA, nodes);
        agg_kernel_f32<<<aggGrid, 256, 0, stream>>>(adj, hA, hB);
        final_partial<<<B_ * 32, 256, 0, stream>>>(hB, Wfl, partial);
        final_reduce<<<1, 64, 0, stream>>>(partial, bfl, out);
    }
}

// Round 5
// 545.206 us; speedup vs baseline: 1.6597x; 1.1266x over previous
//
#include <hip/hip_runtime.h>

#define B_ 4
#define N_ 8192
#define C_ 16
#define JT 512
#define NT (N_ / JT)     // 16 tiles
#define LSTR (JT + 8)    // 520 halves row stride in LDS

typedef _Float16 f16;
typedef f16   f16x2 __attribute__((ext_vector_type(2)));
typedef f16   f16x8 __attribute__((ext_vector_type(8)));
typedef float fv4   __attribute__((ext_vector_type(4)));
typedef unsigned int ui2 __attribute__((ext_vector_type(2)));

union v8u { f16x8 v8; f16x2 v2[4]; unsigned int u[4]; };

// v_dot2_f32_f16: d = a.x*b.x + a.y*b.y + c (f32 accumulate, full-rate VALU)
__device__ __forceinline__ float fdot2(f16x2 a, f16x2 b, float c) {
    float d;
    asm("v_dot2_f32_f16 %0, %1, %2, %3" : "=v"(d) : "v"(a), "v"(b), "v"(c));
    return d;
}

#define DOT8(accv, au, hu)                          \
    do {                                            \
        accv = fdot2((au).v2[0], (hu).v2[0], accv); \
        accv = fdot2((au).v2[1], (hu).v2[1], accv); \
        accv = fdot2((au).v2[2], (hu).v2[2], accv); \
        accv = fdot2((au).v2[3], (hu).v2[3], accv); \
    } while (0)

// ---- 8-bit adjacency code: code = (f16_bits + 32) >> 6  (non-neg, value < 2.0)
//      decode: f16_bits = code << 6.  4-bit mantissa, exact exponent handling.
__device__ __forceinline__ unsigned int enc1(float f) {
    f16 h = (f16)f;
    unsigned short us = __builtin_bit_cast(unsigned short, h);
    return ((unsigned int)us + 32u) >> 6;   // <= 240
}

// decode one dword of 4 codes -> two f16x2 pairs (b0,b1),(b2,b3)
__device__ __forceinline__ void dec4(unsigned int d, f16x2& p01, f16x2& p23) {
#if __has_builtin(__builtin_amdgcn_perm)
    unsigned int t0 = __builtin_amdgcn_perm(d, d, 0x0C010C00u) << 6;
    unsigned int t1 = __builtin_amdgcn_perm(d, d, 0x0C030C02u) << 6;
#else
    unsigned int t0 = ((d & 0xFFu) | ((d << 8) & 0x00FF0000u)) << 6;
    unsigned int t1 = (((d >> 16) & 0xFFu) | ((d >> 8) & 0x00FF0000u)) << 6;
#endif
    p01 = __builtin_bit_cast(f16x2, t0);
    p23 = __builtin_bit_cast(f16x2, t1);
}

__device__ __forceinline__ void dec8(ui2 d, v8u& out) {
    dec4(d.x, out.v2[0], out.v2[1]);
    dec4(d.y, out.v2[2], out.v2[3]);
}

// ============ proj_t: hT[b][c][n] = f16( bias[c] + sum_k in[b][n][k] * W[c][k] ) ============
__global__ __launch_bounds__(256) void proj_t_kernel(const float* __restrict__ hin,
                                                     const float* __restrict__ W,
                                                     const float* __restrict__ bias,
                                                     f16* __restrict__ hT) {
    __shared__ float Ws[C_ * C_];
    __shared__ float bs[C_];
    int t = threadIdx.x;
    Ws[t] = W[t];
    if (t < C_) bs[t] = bias[t];
    __syncthreads();
    int nn = blockIdx.x * 256 + t;
    int b = nn >> 13, n = nn & (N_ - 1);
    const fv4* hv = (const fv4*)(hin + (size_t)nn * C_);
    fv4 q0 = hv[0], q1 = hv[1], q2 = hv[2], q3 = hv[3];
    float hr[16] = {q0[0], q0[1], q0[2], q0[3], q1[0], q1[1], q1[2], q1[3],
                    q2[0], q2[1], q2[2], q2[3], q3[0], q3[1], q3[2], q3[3]};
    f16* dst = hT + ((size_t)b * C_) * N_ + n;
#pragma unroll
    for (int c = 0; c < 16; ++c) {
        float s = bs[c];
#pragma unroll
        for (int k = 0; k < 16; ++k) s += hr[k] * Ws[c * 16 + k];
        dst[(size_t)c * N_] = (f16)s;
    }
}

// ============ agg (coalesced, dot2, 8-bit adjacency cache):
// MODE 0: read fp32 adj, write 8-bit codes + deg, fused proj -> hTout
// MODE 1: read codes + deg,                       fused proj -> hTout
// MODE 2: read codes + deg,                       write g fp32 (layer-3 out)
template <int MODE>
__global__ __launch_bounds__(256) void agg_kernel(const float* __restrict__ adjf,
                                                  const unsigned char* __restrict__ adjc,
                                                  unsigned char* __restrict__ adjc_out,
                                                  const f16* __restrict__ hTin,
                                                  float* __restrict__ deg,
                                                  const float* __restrict__ Wp,
                                                  const float* __restrict__ bp,
                                                  f16* __restrict__ hTout,
                                                  float* __restrict__ gout) {
    __shared__ f16 hs[2][C_][LSTR];
    __shared__ float Ws[C_ * C_ + C_];
    __shared__ float accL[4][4][C_ + 1];

    const int b = blockIdx.y;
    const int i0 = blockIdx.x * 16;
    const int t = threadIdx.x;
    const int wave = t >> 6, lane = t & 63;
    const int r0 = i0 + wave * 4;

    if (MODE < 2) {
        Ws[t] = Wp[t];
        if (t < C_) Ws[C_ * C_ + t] = bp[t];
    }

    float dv[4];
    if (MODE > 0) {
#pragma unroll
        for (int r = 0; r < 4; ++r) dv[r] = deg[(size_t)b * N_ + r0 + r];
    }

    const f16* hTb = hTin + (size_t)b * C_ * N_;
    const int srow = t >> 4, schunk = t & 15;

    auto stage = [&](int buf, int jt) {
        const f16* src = hTb + (size_t)srow * N_ + jt + schunk * 8;
#pragma unroll
        for (int k = 0; k < 4; ++k) {
            f16x8 v = *(const f16x8*)(src + k * 128);
            *(f16x8*)&hs[buf][srow][schunk * 8 + k * 128] = v;
        }
    };

    size_t arow[4];
#pragma unroll
    for (int r = 0; r < 4; ++r) arow[r] = ((size_t)b * N_ + (r0 + r)) * (size_t)N_;

    float acc[4][C_];
#pragma unroll
    for (int r = 0; r < 4; ++r)
#pragma unroll
        for (int c = 0; c < C_; ++c) acc[r][c] = 0.f;
    float ds4[4] = {0.f, 0.f, 0.f, 0.f};
    const f16x2 ones = {(f16)1.f, (f16)1.f};

    stage(0, 0);
    for (int tile = 0; tile < NT; ++tile) {
        __syncthreads();
        if (tile + 1 < NT) stage((tile + 1) & 1, (tile + 1) * JT);
        const int buf = tile & 1;
        const int jb = tile * JT + lane * 8;

        v8u av[4];
        if (MODE == 0) {
#pragma unroll
            for (int r = 0; r < 4; ++r) {
                fv4 f0 = __builtin_nontemporal_load((const fv4*)(adjf + arow[r] + jb));
                fv4 f1 = __builtin_nontemporal_load((const fv4*)(adjf + arow[r] + jb) + 1);
                unsigned int c0 = enc1(f0[0]), c1 = enc1(f0[1]), c2 = enc1(f0[2]), c3 = enc1(f0[3]);
                unsigned int c4 = enc1(f1[0]), c5 = enc1(f1[1]), c6 = enc1(f1[2]), c7 = enc1(f1[3]);
                ui2 pk;
                pk.x = c0 | (c1 << 8) | (c2 << 16) | (c3 << 24);
                pk.y = c4 | (c5 << 8) | (c6 << 16) | (c7 << 24);
                __builtin_nontemporal_store(pk, (ui2*)(adjc_out + arow[r] + jb));
                dec8(pk, av[r]);     // use DECODED values -> deg/products consistent
            }
            v8u on; on.v2[0] = ones; on.v2[1] = ones; on.v2[2] = ones; on.v2[3] = ones;
#pragma unroll
            for (int r = 0; r < 4; ++r) DOT8(ds4[r], av[r], on);
        } else {
#pragma unroll
            for (int r = 0; r < 4; ++r) {
                ui2 pk = __builtin_nontemporal_load((const ui2*)(adjc + arow[r] + jb));
                dec8(pk, av[r]);
            }
        }

#pragma unroll
        for (int c = 0; c < C_; ++c) {
            v8u hu;
            hu.v8 = *(const f16x8*)&hs[buf][c][lane * 8];
            DOT8(acc[0][c], av[0], hu);
            DOT8(acc[1][c], av[1], hu);
            DOT8(acc[2][c], av[2], hu);
            DOT8(acc[3][c], av[3], hu);
        }
    }

    // butterfly reduce across 64 lanes
#pragma unroll
    for (int r = 0; r < 4; ++r)
#pragma unroll
        for (int c = 0; c < C_; ++c) {
            float v = acc[r][c];
#pragma unroll
            for (int m = 32; m >= 1; m >>= 1) v += __shfl_xor(v, m, 64);
            acc[r][c] = v;
        }
    if (MODE == 0) {
#pragma unroll
        for (int r = 0; r < 4; ++r) {
            float v = ds4[r];
#pragma unroll
            for (int m = 32; m >= 1; m >>= 1) v += __shfl_xor(v, m, 64);
            dv[r] = v;
        }
        if (lane == 0) {
#pragma unroll
            for (int r = 0; r < 4; ++r) deg[(size_t)b * N_ + r0 + r] = dv[r];
        }
    }

    // LDS bounce so the epilogue can index the c-dimension dynamically (rule #20)
    if (lane == 0) {
#pragma unroll
        for (int r = 0; r < 4; ++r)
#pragma unroll
            for (int c = 0; c < C_; ++c) accL[wave][r][c] = acc[r][c];
    }
    __syncthreads();

    if (lane < C_) {
        const int ec = lane;
        if (MODE < 2) {
#pragma unroll
            for (int r = 0; r < 4; ++r) {
                float p = Ws[C_ * C_ + ec];
#pragma unroll
                for (int c = 0; c < C_; ++c) {
                    float o = accL[wave][r][c] / dv[r];
                    o = o > 0.f ? o : 0.f;
                    p += o * Ws[ec * C_ + c];
                }
                hTout[(size_t)b * C_ * N_ + (size_t)ec * N_ + (r0 + r)] = (f16)p;
            }
        } else {
#pragma unroll
            for (int r = 0; r < 4; ++r) {
                float o = accL[wave][r][ec] / dv[r];
                o = o > 0.f ? o : 0.f;
                gout[((size_t)b * N_ + r0 + r) * C_ + ec] = o;
            }
        }
    }
}

// ============ final: two-stage deterministic reduction ============
__global__ __launch_bounds__(256) void final_partial(const float* __restrict__ g,
                                                     const float* __restrict__ Wfl,
                                                     float* __restrict__ partial) {
    const int bx = blockIdx.x;                 // b*32 + o*16 + chunk
    const int b = bx >> 5, o = (bx >> 4) & 1, chunk = bx & 15;
    const size_t base = (size_t)chunk * 8192;
    const fv4* hv = (const fv4*)(g + (size_t)b * N_ * C_ + base);
    const fv4* wv = (const fv4*)(Wfl + (size_t)o * N_ * C_ + base);
    float s = 0.f;
#pragma unroll
    for (int k = 0; k < 8; ++k) {
        int idx = threadIdx.x + k * 256;
        fv4 a = hv[idx], w = wv[idx];
        s += a[0] * w[0] + a[1] * w[1] + a[2] * w[2] + a[3] * w[3];
    }
#pragma unroll
    for (int m = 32; m >= 1; m >>= 1) s += __shfl_xor(s, m, 64);
    __shared__ float wsum[4];
    if ((threadIdx.x & 63) == 0) wsum[threadIdx.x >> 6] = s;
    __syncthreads();
    if (threadIdx.x == 0) partial[bx] = wsum[0] + wsum[1] + wsum[2] + wsum[3];
}

__global__ void final_reduce(const float* __restrict__ partial,
                             const float* __restrict__ bfl,
                             float* __restrict__ out) {
    int i = threadIdx.x;
    if (i < B_ * 2) {
        float s = bfl[i & 1];
        for (int k = 0; k < 16; ++k) s += partial[i * 16 + k];
        out[i] = s;
    }
}

// ===================== fallback (round-1 fp32 path, known-passing) =====================
__global__ __launch_bounds__(256) void proj_kernel(const float* __restrict__ hin,
                                                   const float* __restrict__ W,
                                                   const float* __restrict__ bias,
                                                   float* __restrict__ hout,
                                                   int total_nodes) {
    __shared__ float Ws[C_ * C_];
    __shared__ float bs[C_];
    int t = threadIdx.x;
    if (t < C_ * C_) Ws[t] = W[t];
    if (t < C_) bs[t] = bias[t];
    __syncthreads();
    int n = blockIdx.x * 256 + t;
    if (n >= total_nodes) return;
    const fv4* hv = (const fv4*)(hin + (size_t)n * C_);
    fv4 q0 = hv[0], q1 = hv[1], q2 = hv[2], q3 = hv[3];
    float hr[16] = {q0[0], q0[1], q0[2], q0[3], q1[0], q1[1], q1[2], q1[3],
                    q2[0], q2[1], q2[2], q2[3], q3[0], q3[1], q3[2], q3[3]};
    float o[16];
#pragma unroll
    for (int c = 0; c < 16; ++c) {
        float s = bs[c];
#pragma unroll
        for (int k = 0; k < 16; ++k) s += hr[k] * Ws[c * 16 + k];
        o[c] = s;
    }
    fv4* ov = (fv4*)(hout + (size_t)n * C_);
    ov[0] = fv4{o[0], o[1], o[2], o[3]};
    ov[1] = fv4{o[4], o[5], o[6], o[7]};
    ov[2] = fv4{o[8], o[9], o[10], o[11]};
    ov[3] = fv4{o[12], o[13], o[14], o[15]};
}

__global__ __launch_bounds__(256) void agg_kernel_f32(const float* __restrict__ adj,
                                                      const float* __restrict__ hin,
                                                      float* __restrict__ hout) {
    __shared__ fv4 hsf[JT][5];
    const int b = blockIdx.y;
    const int i0 = blockIdx.x * 16;
    const int t = threadIdx.x;
    const int wave = t >> 6;
    const int lane = t & 63;
    const int r0 = i0 + wave * 4;
    const float* adjb = adj + (size_t)b * N_ * N_;
    const float* hb = hin + (size_t)b * N_ * C_;
    const float* ar[4];
#pragma unroll
    for (int r = 0; r < 4; ++r) ar[r] = adjb + (size_t)(r0 + r) * N_;
    float acc[4][16];
#pragma unroll
    for (int r = 0; r < 4; ++r)
#pragma unroll
        for (int c = 0; c < 16; ++c) acc[r][c] = 0.f;
    float rs[4] = {0.f, 0.f, 0.f, 0.f};
    for (int jt = 0; jt < N_; jt += JT) {
        const fv4* src = (const fv4*)(hb + (size_t)jt * C_);
#pragma unroll
        for (int k = 0; k < (JT * C_ / 4) / 256; ++k) {
            int g = t + k * 256;
            hsf[g >> 2][g & 3] = src[g];
        }
        __syncthreads();
#pragma unroll 2
        for (int jj = lane; jj < JT; jj += 64) {
            fv4 q0 = hsf[jj][0], q1 = hsf[jj][1], q2 = hsf[jj][2], q3 = hsf[jj][3];
            float hv[16] = {q0[0], q0[1], q0[2], q0[3], q1[0], q1[1], q1[2], q1[3],
                            q2[0], q2[1], q2[2], q2[3], q3[0], q3[1], q3[2], q3[3]};
#pragma unroll
            for (int r = 0; r < 4; ++r) {
                float av = ar[r][jt + jj];
                rs[r] += av;
#pragma unroll
                for (int c = 0; c < 16; ++c) acc[r][c] += av * hv[c];
            }
        }
        __syncthreads();
    }
#pragma unroll
    for (int r = 0; r < 4; ++r) {
#pragma unroll
        for (int c = 0; c < 16; ++c) {
            float v = acc[r][c];
            for (int mm = 32; mm >= 1; mm >>= 1) v += __shfl_xor(v, mm, 64);
            acc[r][c] = v;
        }
        float d = rs[r];
        for (int mm = 32; mm >= 1; mm >>= 1) d += __shfl_xor(d, mm, 64);
        rs[r] = d;
    }
    if (lane == 0) {
#pragma unroll
        for (int r = 0; r < 4; ++r) {
            float inv = 1.0f / rs[r];
            fv4* dst = (fv4*)(hout + (size_t)b * N_ * C_ + (size_t)(r0 + r) * C_);
#pragma unroll
            for (int q = 0; q < 4; ++q) {
                fv4 ov;
#pragma unroll
                for (int e = 0; e < 4; ++e) {
                    float v = acc[r][q * 4 + e] * inv;
                    ov[e] = v > 0.f ? v : 0.f;
                }
                dst[q] = ov;
            }
        }
    }
}

// ========================================================================================
extern "C" void kernel_launch(void* const* d_in, const int* in_sizes, int n_in,
                              void* d_out, int out_size, void* d_ws, size_t ws_size,
                              hipStream_t stream) {
    const float* x   = (const float*)d_in[0];
    const float* adj = (const float*)d_in[1];
    const float* Wp  = (const float*)d_in[2];
    const float* bp  = (const float*)d_in[3];
    const float* Wfl = (const float*)d_in[4];
    const float* bfl = (const float*)d_in[5];
    float* out = (float*)d_out;

    const size_t adjc_b = (size_t)B_ * N_ * N_;                 // 256 MB (1B codes)
    const size_t deg_b  = (size_t)B_ * N_ * sizeof(float);      // 128 KB
    const size_t hT_b   = (size_t)B_ * C_ * N_ * sizeof(f16);   // 1 MB
    const size_t g_b    = (size_t)B_ * N_ * C_ * sizeof(float); // 2 MB
    const size_t part_b = 128 * sizeof(float);

    if (ws_size >= adjc_b + deg_b + 2 * hT_b + g_b + part_b) {
        char* p = (char*)d_ws;
        unsigned char* adjc = (unsigned char*)p; p += adjc_b;
        float* deg     = (float*)p; p += deg_b;
        f16* hTa       = (f16*)p;   p += hT_b;
        f16* hTb       = (f16*)p;   p += hT_b;
        float* g       = (float*)p; p += g_b;
        float* partial = (float*)p;

        dim3 ag(N_ / 16, B_);
        const int pblocks = B_ * N_ / 256;

        proj_t_kernel<<<pblocks, 256, 0, stream>>>(x, Wp, bp, hTa);
        agg_kernel<0><<<ag, 256, 0, stream>>>(adj, nullptr, adjc, hTa, deg, Wp, bp, hTb, nullptr);
        agg_kernel<1><<<ag, 256, 0, stream>>>(nullptr, adjc, nullptr, hTb, deg, Wp, bp, hTa, nullptr);
        agg_kernel<2><<<ag, 256, 0, stream>>>(nullptr, adjc, nullptr, hTa, deg, Wp, bp, nullptr, g);
        final_partial<<<B_ * 32, 256, 0, stream>>>(g, Wfl, partial);
        final_reduce<<<1, 64, 0, stream>>>(partial, bfl, out);
    } else {
        float* hA = (float*)d_ws;
        float* hB = hA + (size_t)B_ * N_ * C_;
        float* partial = hB + (size_t)B_ * N_ * C_;
        const int nodes = B_ * N_;
        dim3 aggGrid(N_ / 16, B_);
        proj_kernel<<<(nodes + 255) / 256, 256, 0, stream>>>(x, Wp, bp, hA, nodes);
        agg_kernel_f32<<<aggGrid, 256, 0, stream>>>(adj, hA, hB);
        proj_kernel<<<(nodes + 255) / 256, 256, 0, stream>>>(hB, Wp, bp, hA, nodes);
        agg_kernel_f32<<<aggGrid, 256, 0, stream>>>(adj, hA, hB);
        proj_kernel<<<(nodes + 255) / 256, 256, 0, stream>>>(hB, Wp, bp, hA, nodes);
        agg_kernel_f32<<<aggGrid, 256, 0, stream>>>(adj, hA, hB);
        final_partial<<<B_ * 32, 256, 0, stream>>>(hB, Wfl, partial);
        final_reduce<<<1, 64, 0, stream>>>(partial, bfl, out);
    }
}